// Round 5
// baseline (224.305 us; speedup 1.0000x reference)
//
#include <hip/hip_runtime.h>

#define BS   8
#define NCH  7
#define PX   409600      // 640*640
#define NBIN 65536
#define NCHK 256
#define EPSF 1e-6f
#define NT   256
#define BPB  400         // blocks per batch-pass: BPB*NT*4px == PX exactly
#define NWAVE 1600       // PX/256 px per wave

__device__ __forceinline__ float sigf(float x) {
    return 1.0f / (1.0f + __expf(-x));
}

__device__ __forceinline__ unsigned wred_u(unsigned v) {
    #pragma unroll
    for (int o = 32; o; o >>= 1) v += __shfl_down(v, o);
    return v;
}

__device__ __forceinline__ float wred_f(float v) {
    #pragma unroll
    for (int o = 32; o; o >>= 1) v += __shfl_down(v, o);
    return v;
}

// =====================================================================================
// two-level coalesced select over chunks[256] / bins[65536] (rare path only)
// =====================================================================================
__device__ void select2(const unsigned* __restrict__ chunks,
                        const unsigned* __restrict__ bins,
                        unsigned k, unsigned* out_bin, unsigned* out_rank) {
    __shared__ unsigned cs[256];
    int t = threadIdx.x;
    cs[t] = chunks[t];
    __syncthreads();
    #pragma unroll
    for (int off = 1; off < 256; off <<= 1) {
        unsigned v = cs[t];
        unsigned a = (t + off < 256) ? cs[t + off] : 0u;
        __syncthreads();
        cs[t] = v + a;
        __syncthreads();
    }
    {
        unsigned sfx  = cs[t];
        unsigned sfx1 = (t < 255) ? cs[t + 1] : 0u;
        if (sfx >= k && sfx1 < k) { *out_bin = (unsigned)t; *out_rank = k - sfx1; }
    }
    __syncthreads();
    unsigned chunk = *out_bin, krem = *out_rank;
    cs[t] = bins[chunk * 256 + t];
    __syncthreads();
    #pragma unroll
    for (int off = 1; off < 256; off <<= 1) {
        unsigned v = cs[t];
        unsigned a = (t + off < 256) ? cs[t + off] : 0u;
        __syncthreads();
        cs[t] = v + a;
        __syncthreads();
    }
    {
        unsigned sfx  = cs[t];
        unsigned sfx1 = (t < 255) ? cs[t + 1] : 0u;
        if (sfx >= krem && sfx1 < krem) {
            *out_bin  = chunk * 256 + (unsigned)t;
            *out_rank = krem - sfx1;
        }
    }
    __syncthreads();
}

// =====================================================================================
// kA: ch6 pass. 3 loads / 3 accumulators per thread -> full load concurrency.
//   - pn = sigmoid(pred6)*mask; W-bit per pixel packed via __ballot (4 u64 / wave)
//   - pos/zero counts via popcount; 3 speculative (M=1) L_c partial sums
// =====================================================================================
__global__ __launch_bounds__(256) void k_a(
        const float* __restrict__ preds, const int* __restrict__ labels,
        const int* __restrict__ mask,
        float* __restrict__ psumA,           // [BS][3][BPB]
        unsigned* __restrict__ ppos,         // [BS][BPB]
        unsigned* __restrict__ pzero,        // [BS][BPB]
        unsigned long long* __restrict__ wm, // [BS][NWAVE][4]
        unsigned* __restrict__ done) {
    const int tid = threadIdx.x;
    const int b = blockIdx.y, cb = blockIdx.x;
    if (b == 0 && cb == 0 && tid == 0) *done = 0u;   // re-arm k_sel ticket

    const int g  = cb * NT + tid;          // 0..102399
    const int px = g * 4;
    const float* pr6 = preds + ((size_t)b * NCH + 6) * PX;
    const int*   lb6 = labels + ((size_t)b * NCH + 6) * PX;
    const int*   mk  = mask + (size_t)b * PX;

    float4 p6 = *(const float4*)(pr6 + px);
    int4   l6 = *(const int4*)(lb6 + px);
    int4   m4 = *(const int4*)(mk + px);

    float mm[4]  = {(float)m4.x, (float)m4.y, (float)m4.z, (float)m4.w};
    float p6a[4] = {p6.x, p6.y, p6.z, p6.w};
    float l6a[4] = {(float)l6.x, (float)l6.y, (float)l6.z, (float)l6.w};

    float pn[4];
    unsigned long long bp[4], bz[4];
    #pragma unroll
    for (int u = 0; u < 4; u++) {
        pn[u] = sigf(p6a[u]) * mm[u];
        bp[u] = __ballot(pn[u] >= 0.5f);
        bz[u] = __ballot(__float_as_uint(pn[u]) == 0u);   // pn==0 <=> mask==0 (sig>0)
    }

    // spec (M=1) L_c sums
    float a0 = 0.f, a1 = 0.f, a2 = 0.f;
    #pragma unroll
    for (int u = 0; u < 4; u++) {
        float ln = l6a[u] * mm[u];
        a0 += pn[u] * ln;
        a1 += pn[u] * pn[u];
        a2 += ln;
    }

    const int lane = tid & 63, wid = tid >> 6;
    const int w = g >> 6;                  // wave index within batch, 0..NWAVE-1
    if (lane == 0) {
        ulonglong2* wp = (ulonglong2*)(wm + ((size_t)b * NWAVE + w) * 4);
        wp[0] = make_ulonglong2(bp[0], bp[1]);
        wp[1] = make_ulonglong2(bp[2], bp[3]);
    }

    // counts (ballot results are wave-uniform)
    __shared__ unsigned cpos[4], czer[4];
    if (lane == 0) {
        cpos[wid] = (unsigned)(__popcll(bp[0]) + __popcll(bp[1]) +
                               __popcll(bp[2]) + __popcll(bp[3]));
        czer[wid] = (unsigned)(__popcll(bz[0]) + __popcll(bz[1]) +
                               __popcll(bz[2]) + __popcll(bz[3]));
    }
    __shared__ float red[4][3];
    float v0 = wred_f(a0), v1 = wred_f(a1), v2 = wred_f(a2);
    if (lane == 0) { red[wid][0] = v0; red[wid][1] = v1; red[wid][2] = v2; }
    __syncthreads();
    if (tid < 3) {
        float tot = red[0][tid] + red[1][tid] + red[2][tid] + red[3][tid];
        psumA[((size_t)b * 3 + tid) * BPB + cb] = tot;
    }
    if (tid == 3) ppos[b * BPB + cb]  = cpos[0] + cpos[1] + cpos[2] + cpos[3];
    if (tid == 4) pzero[b * BPB + cb] = czer[0] + czer[1] + czer[2] + czer[3];
}

// =====================================================================================
// kB: one block per (batch, channel<6) slice. 2 data loads + 1 broadcast W-mask load,
// 3 accumulators -> VGPR-lean, full occupancy, all loads in flight. BW-bound by design.
// =====================================================================================
__global__ __launch_bounds__(256) void k_b(
        const float* __restrict__ preds, const int* __restrict__ labels,
        const unsigned long long* __restrict__ wm,
        float* __restrict__ psumB) {        // [BS*6][3][BPB]
    const int tid = threadIdx.x;
    const int y = blockIdx.y;               // b*6 + c
    const int b = y / 6, c = y % 6;
    const int cb = blockIdx.x;
    const int g  = cb * NT + tid;
    const int px = g * 4;
    const float* pc = preds + ((size_t)b * NCH + c) * PX;
    const int*   lc = labels + ((size_t)b * NCH + c) * PX;

    float4 p = *(const float4*)(pc + px);
    int4   l = *(const int4*)(lc + px);
    const int lane = tid & 63, wid = tid >> 6;
    const int w = g >> 6;
    const ulonglong2* wp = (const ulonglong2*)(wm + ((size_t)b * NWAVE + w) * 4);
    ulonglong2 w01 = wp[0];                 // wave-uniform -> L1 broadcast
    ulonglong2 w23 = wp[1];

    float W[4] = { (float)((w01.x >> lane) & 1ull), (float)((w01.y >> lane) & 1ull),
                   (float)((w23.x >> lane) & 1ull), (float)((w23.y >> lane) & 1ull) };
    float pa[4] = {p.x, p.y, p.z, p.w};
    float la[4] = {(float)l.x, (float)l.y, (float)l.z, (float)l.w};

    float sn = 0.f, sp = 0.f, sl = 0.f;
    #pragma unroll
    for (int u = 0; u < 4; u++) {
        float s  = sigf(pa[u]);
        float lw = la[u] * W[u];
        sn += s * lw;            // sum S*G
        sp += s * s * W[u];      // sum S*S
        sl += lw;                // sum G*G  (G in {0,1})
    }

    __shared__ float red[4][3];
    float v0 = wred_f(sn), v1 = wred_f(sp), v2 = wred_f(sl);
    if (lane == 0) { red[wid][0] = v0; red[wid][1] = v1; red[wid][2] = v2; }
    __syncthreads();
    if (tid < 3) {
        float tot = red[0][tid] + red[1][tid] + red[2][tid] + red[3][tid];
        psumB[((size_t)y * 3 + tid) * BPB + cb] = tot;
    }
}

// =====================================================================================
// k_sel: 8 blocks, one per batch. Reduce all partials; fast path (always hit on bench
// data): thr<=0 or k >= nonzero-negatives -> speculative sums exact. Rare path: solo
// exact selection + rescan. 8-block ticket emits final losses.
// =====================================================================================
__global__ __launch_bounds__(256) void k_sel(
        const float* __restrict__ preds, const int* __restrict__ labels,
        const int* __restrict__ mask,
        const float* __restrict__ psumA, const float* __restrict__ psumB,
        const unsigned* __restrict__ ppos, const unsigned* __restrict__ pzero,
        unsigned* __restrict__ histws, unsigned* __restrict__ chunkws,
        float* __restrict__ lcls, unsigned* __restrict__ done,
        float* __restrict__ out) {
    const int tid = threadIdx.x;
    const int b = blockIdx.x;
    const int lane = tid & 63, wid = tid >> 6;

    // ---- reduce counts + 21 sums into LDS ----
    __shared__ float S[21];
    __shared__ unsigned C[2];
    if (tid < 21) S[tid] = 0.f;
    if (tid < 2) C[tid] = 0u;
    __syncthreads();
    {
        unsigned pc = 0, zc = 0;
        for (int i = tid; i < BPB; i += NT) {
            pc += ppos[b * BPB + i];
            zc += pzero[b * BPB + i];
        }
        pc = wred_u(pc); zc = wred_u(zc);
        if (lane == 0) { atomicAdd(&C[0], pc); atomicAdd(&C[1], zc); }
    }
    for (int i = tid; i < 3 * BPB; i += NT)
        atomicAdd(&S[18 + i / BPB], psumA[(size_t)b * 3 * BPB + i]);
    for (int i = tid; i < 18 * BPB; i += NT) {
        int cch = i / (3 * BPB);
        int j   = (i / BPB) % 3;
        atomicAdd(&S[j * 6 + cch], psumB[(size_t)b * 18 * BPB + i]);
    }
    __syncthreads();
    const unsigned np = C[0], zc = C[1];

    const unsigned k = np * 3u;
    const bool active = ((unsigned)PX - np > k) && (k > 0u);
    const unsigned nzneg = (unsigned)PX - np - zc;   // negatives with pn > 0

    float Lc_b;
    if (!active || k >= nzneg) {
        // thr <= 0: excluded pixels all have pn==0 => mask==0 => zero contribution.
        Lc_b = 1.0f - 2.0f * S[18] / (S[19] + S[20] + EPSF);
    } else {
        // -------- RARE exact path (not hit by bench data; correctness only) --------
        unsigned* h1 = histws + (size_t)b * NBIN;
        unsigned* c1 = chunkws + (size_t)b * NCHK;
        const float* pr6 = preds + ((size_t)b * NCH + 6) * PX;
        const int*   lb6 = labels + ((size_t)b * NCH + 6) * PX;
        const int*   mk  = mask + (size_t)b * PX;

        for (int j = tid; j < NBIN; j += NT) h1[j] = 0u;
        for (int j = tid; j < NCHK; j += NT) c1[j] = 0u;
        __syncthreads();
        for (int gg = tid; gg < PX; gg += NT) {
            float pnx = sigf(pr6[gg]) * (float)mk[gg];
            if (pnx < 0.5f) {
                unsigned bits = __float_as_uint(pnx);
                if (bits) {
                    atomicAdd(&h1[bits >> 16], 1u);
                    atomicAdd(&c1[bits >> 24], 1u);
                }
            }
        }
        __syncthreads();
        if (tid == 0) { atomicAdd(&h1[0], zc); atomicAdd(&c1[0], zc); }
        __syncthreads();

        __shared__ unsigned rb, rr, rb2, rr2;
        select2(c1, h1, k, &rb, &rr);
        float thrv;
        if (rb == 0u) {
            thrv = 0.0f;
        } else {
            unsigned hi = rb;
            for (int j = tid; j < NBIN; j += NT) h1[j] = 0u;
            for (int j = tid; j < NCHK; j += NT) c1[j] = 0u;
            __syncthreads();
            for (int gg = tid; gg < PX; gg += NT) {
                float pnx = sigf(pr6[gg]) * (float)mk[gg];
                if (pnx < 0.5f) {
                    unsigned bits = __float_as_uint(pnx);
                    if (bits && (bits >> 16) == hi) {
                        unsigned lo = bits & 0xFFFFu;
                        atomicAdd(&h1[lo], 1u);
                        atomicAdd(&c1[lo >> 8], 1u);
                    }
                }
            }
            __syncthreads();
            select2(c1, h1, rr, &rb2, &rr2);
            thrv = __uint_as_float((hi << 16) | rb2);
        }
        float a0 = 0.f, a1 = 0.f, a2 = 0.f;
        for (int gg = tid; gg < PX; gg += NT) {
            float m   = (float)mk[gg];
            float pnx = sigf(pr6[gg]) * m;
            if (pnx >= thrv) {
                float ln = (float)lb6[gg] * m;
                a0 += pnx * ln;
                a1 += pnx * pnx;
                a2 += ln;
            }
        }
        __shared__ float aR[4][3];
        float v0 = wred_f(a0), v1 = wred_f(a1), v2 = wred_f(a2);
        if (lane == 0) { aR[wid][0] = v0; aR[wid][1] = v1; aR[wid][2] = v2; }
        __syncthreads();
        float A0 = aR[0][0] + aR[1][0] + aR[2][0] + aR[3][0];
        float A1 = aR[0][1] + aR[1][1] + aR[2][1] + aR[3][1];
        float A2 = aR[0][2] + aR[1][2] + aR[2][2] + aR[3][2];
        Lc_b = 1.0f - 2.0f * A0 / (A1 + A2 + EPSF);
    }

    float ls_acc = 0.f;
    #pragma unroll
    for (int c = 0; c < 6; c++)
        ls_acc += (2.0f * S[c]) / (S[6 + c] + S[12 + c] + EPSF);
    float Ls_b = 1.0f - ls_acc * (1.0f / 6.0f);

    if (tid == 0) {
        lcls[b * 2]     = Lc_b;
        lcls[b * 2 + 1] = Ls_b;
    }

    // ---- 8-block ticket -> last block emits final losses ----
    __shared__ unsigned tick;
    if (tid == 0) {
        __threadfence();
        tick = atomicAdd(done, 1u);
    }
    __syncthreads();
    if (tick != (unsigned)(BS - 1)) return;
    __threadfence();

    float Lc = 0.f, Ls = 0.f;
    if (tid < BS) { Lc = lcls[tid * 2]; Ls = lcls[tid * 2 + 1]; }
    #pragma unroll
    for (int o = 4; o; o >>= 1) { Lc += __shfl_down(Lc, o); Ls += __shfl_down(Ls, o); }
    if (tid == 0) {
        float lc_m = Lc * (1.0f / (float)BS);
        float ls_m = Ls * (1.0f / (float)BS);
        out[0] = lc_m;
        out[1] = ls_m;
        out[2] = 0.7f * lc_m + 0.3f * ls_m;
    }
}

extern "C" void kernel_launch(void* const* d_in, const int* in_sizes, int n_in,
                              void* d_out, int out_size, void* d_ws, size_t ws_size,
                              hipStream_t stream) {
    const float* preds = (const float*)d_in[0];
    const int* labels  = (const int*)d_in[1];
    const int* mask    = (const int*)d_in[2];
    float* out = (float*)d_out;

    // workspace (nothing needs pre-zeroing)
    float*    psumA  = (float*)d_ws;                           // BS*3*BPB
    float*    psumB  = psumA + (size_t)BS * 3 * BPB;           // BS*6*3*BPB
    unsigned* ppos   = (unsigned*)(psumB + (size_t)BS * 18 * BPB); // BS*BPB
    unsigned* pzero  = ppos + BS * BPB;                        // BS*BPB
    unsigned* done   = pzero + BS * BPB;                       // 1 (pad 8)
    float*    lcls   = (float*)(done + 8);                     // BS*2
    unsigned long long* wm = (unsigned long long*)(lcls + BS * 2 + 2); // BS*NWAVE*4 (8B-align ok: offset even)
    unsigned* histws = (unsigned*)(wm + (size_t)BS * NWAVE * 4);   // BS*NBIN (rare)
    unsigned* chunkws = histws + (size_t)BS * NBIN;                // BS*NCHK (rare)

    hipLaunchKernelGGL(k_a, dim3(BPB, BS), dim3(NT), 0, stream,
                       preds, labels, mask, psumA, ppos, pzero, wm, done);

    hipLaunchKernelGGL(k_b, dim3(BPB, BS * 6), dim3(NT), 0, stream,
                       preds, labels, wm, psumB);

    hipLaunchKernelGGL(k_sel, dim3(BS), dim3(NT), 0, stream,
                       preds, labels, mask, psumA, psumB, ppos, pzero,
                       histws, chunkws, lcls, done, out);
}

// Round 6
// 217.274 us; speedup vs baseline: 1.0324x; 1.0324x over previous
//
#include <hip/hip_runtime.h>

#define BS   8
#define NCH  7
#define PX   409600      // 640*640
#define NBIN 65536
#define NCHK 256
#define EPSF 1e-6f
#define NT   256
#define GXA  200         // k_a blocks per batch; GXA*NT*UA == PX/4
#define UA   2
#define GXB  50          // k_b blocks per (batch,channel); GXB*NT*UB*ITB == PX/4
#define UB   4
#define ITB  2
#define NWAVE 1600       // waves per batch = (PX/4)/64

__device__ __forceinline__ float sigf(float x) {
    return 1.0f / (1.0f + __expf(-x));
}

__device__ __forceinline__ unsigned wred_u(unsigned v) {
    #pragma unroll
    for (int o = 32; o; o >>= 1) v += __shfl_down(v, o);
    return v;
}

__device__ __forceinline__ float wred_f(float v) {
    #pragma unroll
    for (int o = 32; o; o >>= 1) v += __shfl_down(v, o);
    return v;
}

// interleaved 3-value wave reduction: 3 independent chains overlap the ds-permute latency
__device__ __forceinline__ void wred3_f(float& v0, float& v1, float& v2) {
    #pragma unroll
    for (int o = 32; o; o >>= 1) {
        float t0 = __shfl_down(v0, o);
        float t1 = __shfl_down(v1, o);
        float t2 = __shfl_down(v2, o);
        v0 += t0; v1 += t1; v2 += t2;
    }
}

// =====================================================================================
// two-level coalesced select over chunks[256] / bins[65536] (rare path only)
// =====================================================================================
__device__ void select2(const unsigned* __restrict__ chunks,
                        const unsigned* __restrict__ bins,
                        unsigned k, unsigned* out_bin, unsigned* out_rank) {
    __shared__ unsigned cs[256];
    int t = threadIdx.x;
    cs[t] = chunks[t];
    __syncthreads();
    #pragma unroll
    for (int off = 1; off < 256; off <<= 1) {
        unsigned v = cs[t];
        unsigned a = (t + off < 256) ? cs[t + off] : 0u;
        __syncthreads();
        cs[t] = v + a;
        __syncthreads();
    }
    {
        unsigned sfx  = cs[t];
        unsigned sfx1 = (t < 255) ? cs[t + 1] : 0u;
        if (sfx >= k && sfx1 < k) { *out_bin = (unsigned)t; *out_rank = k - sfx1; }
    }
    __syncthreads();
    unsigned chunk = *out_bin, krem = *out_rank;
    cs[t] = bins[chunk * 256 + t];
    __syncthreads();
    #pragma unroll
    for (int off = 1; off < 256; off <<= 1) {
        unsigned v = cs[t];
        unsigned a = (t + off < 256) ? cs[t + off] : 0u;
        __syncthreads();
        cs[t] = v + a;
        __syncthreads();
    }
    {
        unsigned sfx  = cs[t];
        unsigned sfx1 = (t < 255) ? cs[t + 1] : 0u;
        if (sfx >= krem && sfx1 < krem) {
            *out_bin  = chunk * 256 + (unsigned)t;
            *out_rank = krem - sfx1;
        }
    }
    __syncthreads();
}

// =====================================================================================
// kA: ch6 pass, 2 groups/thread batched (6 dwordx4 in flight).
//   W-bit per pixel via __ballot -> wm; pos/zero via popcount; 3 spec (M=1) L_c sums.
// =====================================================================================
__global__ __launch_bounds__(256) void k_a(
        const float* __restrict__ preds, const int* __restrict__ labels,
        const int* __restrict__ mask,
        float* __restrict__ psumA,           // [BS][3][GXA]
        unsigned* __restrict__ ppos,         // [BS][GXA]
        unsigned* __restrict__ pzero,        // [BS][GXA]
        unsigned long long* __restrict__ wm, // [BS][NWAVE][4]
        unsigned* __restrict__ done) {
    const int tid = threadIdx.x;
    const int b = blockIdx.y, cb = blockIdx.x;
    if (b == 0 && cb == 0 && tid == 0) *done = 0u;   // re-arm k_sel ticket

    const float* pr6 = preds + ((size_t)b * NCH + 6) * PX;
    const int*   lb6 = labels + ((size_t)b * NCH + 6) * PX;
    const int*   mk  = mask + (size_t)b * PX;
    const int g0 = cb * (NT * UA) + tid;
    const int lane = tid & 63, wid = tid >> 6;

    // ---- batch all loads (6 dwordx4 in flight) ----
    float4 P[UA]; int4 L[UA]; int4 M[UA];
    #pragma unroll
    for (int q = 0; q < UA; q++) {
        int px = (g0 + q * NT) * 4;
        P[q] = *(const float4*)(pr6 + px);
        L[q] = *(const int4*)(lb6 + px);
        M[q] = *(const int4*)(mk + px);
    }

    float a0 = 0.f, a1 = 0.f;
    unsigned a2c = 0, pos = 0, zer = 0;
    #pragma unroll
    for (int q = 0; q < UA; q++) {
        float mm[4]  = {(float)M[q].x, (float)M[q].y, (float)M[q].z, (float)M[q].w};
        float pa[4]  = {P[q].x, P[q].y, P[q].z, P[q].w};
        int   la[4]  = {L[q].x, L[q].y, L[q].z, L[q].w};
        unsigned long long bp[4];
        #pragma unroll
        for (int v = 0; v < 4; v++) {
            float pn = sigf(pa[v]) * mm[v];
            bp[v] = __ballot(pn >= 0.5f);
            unsigned long long bz = __ballot(__float_as_uint(pn) == 0u);
            pos += (unsigned)__popcll(bp[v]);
            zer += (unsigned)__popcll(bz);
            bool ln = (la[v] != 0) & (M[q].x == M[q].x) & (mm[v] != 0.0f); // l6*m in {0,1}
            a0 += ln ? pn : 0.0f;        // pn * ln
            a1 += pn * pn;
            a2c += ln ? 1u : 0u;         // sum ln
        }
        if (lane == 0) {
            int wv = (g0 + q * NT) >> 6;
            ulonglong2* wp = (ulonglong2*)(wm + ((size_t)b * NWAVE + wv) * 4);
            wp[0] = make_ulonglong2(bp[0], bp[1]);
            wp[1] = make_ulonglong2(bp[2], bp[3]);
        }
    }

    // ---- block reduce: counts are wave-uniform (from ballots); 3 float chains ----
    __shared__ unsigned cpos[4], czer[4];
    __shared__ float red[4][3];
    if (lane == 0) { cpos[wid] = pos; czer[wid] = zer; }
    float v0 = a0, v1 = a1, v2 = (float)a2c;
    wred3_f(v0, v1, v2);
    if (lane == 0) { red[wid][0] = v0; red[wid][1] = v1; red[wid][2] = v2; }
    __syncthreads();
    if (tid < 3) {
        float tot = red[0][tid] + red[1][tid] + red[2][tid] + red[3][tid];
        psumA[((size_t)b * 3 + tid) * GXA + cb] = tot;
    }
    if (tid == 3) ppos[b * GXA + cb]  = cpos[0] + cpos[1] + cpos[2] + cpos[3];
    if (tid == 4) pzero[b * GXA + cb] = czer[0] + czer[1] + czer[2] + czer[3];
}

// =====================================================================================
// kB: one block per (batch, channel<6, chunk). 8 groups/thread (2 iters x batch-4),
// 8 dwordx4 in flight; W-mask via scalar (s_load) wave-uniform reads; int label folds.
// =====================================================================================
__global__ __launch_bounds__(256) void k_b(
        const float* __restrict__ preds, const int* __restrict__ labels,
        const unsigned long long* __restrict__ wm,
        float* __restrict__ psumB) {        // [BS*6][3][GXB]
    const int tid = threadIdx.x;
    const int y = blockIdx.y;               // b*6 + c
    const int b = y / 6, c = y % 6;
    const int cb = blockIdx.x;
    const int lane = tid & 63;
    const int widu = __builtin_amdgcn_readfirstlane(tid >> 6);  // SGPR wave id
    const float* pc = preds + ((size_t)b * NCH + c) * PX;
    const int*   lc = labels + ((size_t)b * NCH + c) * PX;
    const unsigned long long* wmb = wm + (size_t)b * NWAVE * 4;

    float sn = 0.f, sp = 0.f;
    unsigned slc = 0;

    for (int it = 0; it < ITB; ++it) {
        const int gbase = cb * (NT * UB * ITB) + it * (NT * UB) + tid;
        // ---- batch the 8 data loads ----
        float4 P[UB]; int4 L[UB];
        #pragma unroll
        for (int q = 0; q < UB; q++) {
            int px = (gbase + q * NT) * 4;
            P[q] = *(const float4*)(pc + px);
            L[q] = *(const int4*)(lc + px);
        }
        // ---- wave-uniform W-mask loads (scalar path) ----
        ulonglong2 WA[UB], WB[UB];
        #pragma unroll
        for (int q = 0; q < UB; q++) {
            int wv = ((cb * (NT * UB * ITB) + it * (NT * UB) + q * NT) >> 6) + widu;
            const ulonglong2* wp = (const ulonglong2*)(wmb + (size_t)wv * 4);
            WA[q] = wp[0];
            WB[q] = wp[1];
        }
        #pragma unroll
        for (int q = 0; q < UB; q++) {
            float pa[4] = {P[q].x, P[q].y, P[q].z, P[q].w};
            int   la[4] = {L[q].x, L[q].y, L[q].z, L[q].w};
            unsigned wbit[4] = {
                (unsigned)((WA[q].x >> lane) & 1ull), (unsigned)((WA[q].y >> lane) & 1ull),
                (unsigned)((WB[q].x >> lane) & 1ull), (unsigned)((WB[q].y >> lane) & 1ull) };
            #pragma unroll
            for (int v = 0; v < 4; v++) {
                float s = sigf(pa[v]);
                bool w  = wbit[v] != 0u;
                bool lw = w && (la[v] != 0);
                sn += lw ? s : 0.0f;         // sum S*G*W
                sp += w ? s * s : 0.0f;      // sum S*S*W
                slc += lw ? 1u : 0u;         // sum G*G*W (G in {0,1})
            }
        }
    }

    __shared__ float red[4][3];
    float v0 = sn, v1 = sp, v2 = (float)slc;
    wred3_f(v0, v1, v2);
    if (lane == 0) { red[tid >> 6][0] = v0; red[tid >> 6][1] = v1; red[tid >> 6][2] = v2; }
    __syncthreads();
    if (tid < 3) {
        float tot = red[0][tid] + red[1][tid] + red[2][tid] + red[3][tid];
        psumB[((size_t)y * 3 + tid) * GXB + cb] = tot;
    }
}

// =====================================================================================
// k_sel: 8 blocks, one per batch. Reduce partials; fast path (always hit on bench
// data): thr<=0 or k >= nonzero-negatives -> speculative sums exact. Rare path: solo
// exact selection + rescan. 8-block ticket emits final losses.
// =====================================================================================
__global__ __launch_bounds__(256) void k_sel(
        const float* __restrict__ preds, const int* __restrict__ labels,
        const int* __restrict__ mask,
        const float* __restrict__ psumA, const float* __restrict__ psumB,
        const unsigned* __restrict__ ppos, const unsigned* __restrict__ pzero,
        unsigned* __restrict__ histws, unsigned* __restrict__ chunkws,
        float* __restrict__ lcls, unsigned* __restrict__ done,
        float* __restrict__ out) {
    const int tid = threadIdx.x;
    const int b = blockIdx.x;
    const int lane = tid & 63, wid = tid >> 6;

    // ---- reduce counts + 21 sums into LDS ----
    __shared__ float S[21];
    __shared__ unsigned C[2];
    if (tid < 21) S[tid] = 0.f;
    if (tid < 2) C[tid] = 0u;
    __syncthreads();
    {
        unsigned pc = 0, zc = 0;
        for (int i = tid; i < GXA; i += NT) {
            pc += ppos[b * GXA + i];
            zc += pzero[b * GXA + i];
        }
        pc = wred_u(pc); zc = wred_u(zc);
        if (lane == 0) { atomicAdd(&C[0], pc); atomicAdd(&C[1], zc); }
    }
    for (int i = tid; i < 3 * GXA; i += NT)
        atomicAdd(&S[18 + i / GXA], psumA[(size_t)b * 3 * GXA + i]);
    for (int i = tid; i < 6 * 3 * GXB; i += NT) {
        int cch = i / (3 * GXB);
        int j   = (i / GXB) % 3;
        atomicAdd(&S[j * 6 + cch], psumB[(size_t)b * 6 * 3 * GXB + i]);
    }
    __syncthreads();
    const unsigned np = C[0], zc = C[1];

    const unsigned k = np * 3u;
    const bool active = ((unsigned)PX - np > k) && (k > 0u);
    const unsigned nzneg = (unsigned)PX - np - zc;   // negatives with pn > 0

    float Lc_b;
    if (!active || k >= nzneg) {
        // thr <= 0: excluded pixels all have pn==0 => mask==0 => zero contribution.
        Lc_b = 1.0f - 2.0f * S[18] / (S[19] + S[20] + EPSF);
    } else {
        // -------- RARE exact path (not hit by bench data; correctness only) --------
        unsigned* h1 = histws + (size_t)b * NBIN;
        unsigned* c1 = chunkws + (size_t)b * NCHK;
        const float* pr6 = preds + ((size_t)b * NCH + 6) * PX;
        const int*   lb6 = labels + ((size_t)b * NCH + 6) * PX;
        const int*   mk  = mask + (size_t)b * PX;

        for (int j = tid; j < NBIN; j += NT) h1[j] = 0u;
        for (int j = tid; j < NCHK; j += NT) c1[j] = 0u;
        __syncthreads();
        for (int gg = tid; gg < PX; gg += NT) {
            float pnx = sigf(pr6[gg]) * (float)mk[gg];
            if (pnx < 0.5f) {
                unsigned bits = __float_as_uint(pnx);
                if (bits) {
                    atomicAdd(&h1[bits >> 16], 1u);
                    atomicAdd(&c1[bits >> 24], 1u);
                }
            }
        }
        __syncthreads();
        if (tid == 0) { atomicAdd(&h1[0], zc); atomicAdd(&c1[0], zc); }
        __syncthreads();

        __shared__ unsigned rb, rr, rb2, rr2;
        select2(c1, h1, k, &rb, &rr);
        float thrv;
        if (rb == 0u) {
            thrv = 0.0f;
        } else {
            unsigned hi = rb;
            for (int j = tid; j < NBIN; j += NT) h1[j] = 0u;
            for (int j = tid; j < NCHK; j += NT) c1[j] = 0u;
            __syncthreads();
            for (int gg = tid; gg < PX; gg += NT) {
                float pnx = sigf(pr6[gg]) * (float)mk[gg];
                if (pnx < 0.5f) {
                    unsigned bits = __float_as_uint(pnx);
                    if (bits && (bits >> 16) == hi) {
                        unsigned lo = bits & 0xFFFFu;
                        atomicAdd(&h1[lo], 1u);
                        atomicAdd(&c1[lo >> 8], 1u);
                    }
                }
            }
            __syncthreads();
            select2(c1, h1, rr, &rb2, &rr2);
            thrv = __uint_as_float((hi << 16) | rb2);
        }
        float a0 = 0.f, a1 = 0.f, a2 = 0.f;
        for (int gg = tid; gg < PX; gg += NT) {
            float m   = (float)mk[gg];
            float pnx = sigf(pr6[gg]) * m;
            if (pnx >= thrv) {
                float ln = (float)lb6[gg] * m;
                a0 += pnx * ln;
                a1 += pnx * pnx;
                a2 += ln;
            }
        }
        __shared__ float aR[4][3];
        wred3_f(a0, a1, a2);
        if (lane == 0) { aR[wid][0] = a0; aR[wid][1] = a1; aR[wid][2] = a2; }
        __syncthreads();
        float A0 = aR[0][0] + aR[1][0] + aR[2][0] + aR[3][0];
        float A1 = aR[0][1] + aR[1][1] + aR[2][1] + aR[3][1];
        float A2 = aR[0][2] + aR[1][2] + aR[2][2] + aR[3][2];
        Lc_b = 1.0f - 2.0f * A0 / (A1 + A2 + EPSF);
    }

    float ls_acc = 0.f;
    #pragma unroll
    for (int c = 0; c < 6; c++)
        ls_acc += (2.0f * S[c]) / (S[6 + c] + S[12 + c] + EPSF);
    float Ls_b = 1.0f - ls_acc * (1.0f / 6.0f);

    if (tid == 0) {
        lcls[b * 2]     = Lc_b;
        lcls[b * 2 + 1] = Ls_b;
    }

    // ---- 8-block ticket -> last block emits final losses ----
    __shared__ unsigned tick;
    if (tid == 0) {
        __threadfence();
        tick = atomicAdd(done, 1u);
    }
    __syncthreads();
    if (tick != (unsigned)(BS - 1)) return;
    __threadfence();

    float Lc = 0.f, Ls = 0.f;
    if (tid < BS) { Lc = lcls[tid * 2]; Ls = lcls[tid * 2 + 1]; }
    #pragma unroll
    for (int o = 4; o; o >>= 1) { Lc += __shfl_down(Lc, o); Ls += __shfl_down(Ls, o); }
    if (tid == 0) {
        float lc_m = Lc * (1.0f / (float)BS);
        float ls_m = Ls * (1.0f / (float)BS);
        out[0] = lc_m;
        out[1] = ls_m;
        out[2] = 0.7f * lc_m + 0.3f * ls_m;
    }
}

extern "C" void kernel_launch(void* const* d_in, const int* in_sizes, int n_in,
                              void* d_out, int out_size, void* d_ws, size_t ws_size,
                              hipStream_t stream) {
    const float* preds = (const float*)d_in[0];
    const int* labels  = (const int*)d_in[1];
    const int* mask    = (const int*)d_in[2];
    float* out = (float*)d_out;

    // workspace (nothing needs pre-zeroing); wm first for 16B alignment
    unsigned long long* wm = (unsigned long long*)d_ws;        // BS*NWAVE*4
    float*    psumA  = (float*)(wm + (size_t)BS * NWAVE * 4);  // BS*3*GXA
    unsigned* ppos   = (unsigned*)(psumA + (size_t)BS * 3 * GXA); // BS*GXA
    unsigned* pzero  = ppos + BS * GXA;                        // BS*GXA
    float*    psumB  = (float*)(pzero + BS * GXA);             // BS*6*3*GXB
    unsigned* done   = (unsigned*)(psumB + (size_t)BS * 18 * GXB); // 1 (pad 8)
    float*    lcls   = (float*)(done + 8);                     // BS*2
    unsigned* histws = (unsigned*)(lcls + BS * 2);             // BS*NBIN (rare)
    unsigned* chunkws = histws + (size_t)BS * NBIN;            // BS*NCHK (rare)

    hipLaunchKernelGGL(k_a, dim3(GXA, BS), dim3(NT), 0, stream,
                       preds, labels, mask, psumA, ppos, pzero, wm, done);

    hipLaunchKernelGGL(k_b, dim3(GXB, BS * 6), dim3(NT), 0, stream,
                       preds, labels, wm, psumB);

    hipLaunchKernelGGL(k_sel, dim3(BS), dim3(NT), 0, stream,
                       preds, labels, mask, psumA, psumB, ppos, pzero,
                       histws, chunkws, lcls, done, out);
}

// Round 7
// 216.546 us; speedup vs baseline: 1.0358x; 1.0034x over previous
//
#include <hip/hip_runtime.h>

#define BS   8
#define NCH  7
#define PX   409600      // 640*640
#define NBIN 65536
#define NCHK 256
#define EPSF 1e-6f
#define NT   256
#define GXM  50          // blocks per (batch,channel); GXM*NT*UM*ITM*4 == PX
#define UM   4
#define ITM  2

__device__ __forceinline__ float sigf(float x) {
    return 1.0f / (1.0f + __expf(-x));
}

__device__ __forceinline__ unsigned wred_u(unsigned v) {
    #pragma unroll
    for (int o = 32; o; o >>= 1) v += __shfl_down(v, o);
    return v;
}

// interleaved 3-value wave reduction: independent chains overlap ds-permute latency
__device__ __forceinline__ void wred3_f(float& v0, float& v1, float& v2) {
    #pragma unroll
    for (int o = 32; o; o >>= 1) {
        float t0 = __shfl_down(v0, o);
        float t1 = __shfl_down(v1, o);
        float t2 = __shfl_down(v2, o);
        v0 += t0; v1 += t1; v2 += t2;
    }
}

// =====================================================================================
// two-level coalesced select over chunks[256] / bins[65536] (rare path only)
// =====================================================================================
__device__ void select2(const unsigned* __restrict__ chunks,
                        const unsigned* __restrict__ bins,
                        unsigned k, unsigned* out_bin, unsigned* out_rank) {
    __shared__ unsigned cs[256];
    int t = threadIdx.x;
    cs[t] = chunks[t];
    __syncthreads();
    #pragma unroll
    for (int off = 1; off < 256; off <<= 1) {
        unsigned v = cs[t];
        unsigned a = (t + off < 256) ? cs[t + off] : 0u;
        __syncthreads();
        cs[t] = v + a;
        __syncthreads();
    }
    {
        unsigned sfx  = cs[t];
        unsigned sfx1 = (t < 255) ? cs[t + 1] : 0u;
        if (sfx >= k && sfx1 < k) { *out_bin = (unsigned)t; *out_rank = k - sfx1; }
    }
    __syncthreads();
    unsigned chunk = *out_bin, krem = *out_rank;
    cs[t] = bins[chunk * 256 + t];
    __syncthreads();
    #pragma unroll
    for (int off = 1; off < 256; off <<= 1) {
        unsigned v = cs[t];
        unsigned a = (t + off < 256) ? cs[t + off] : 0u;
        __syncthreads();
        cs[t] = v + a;
        __syncthreads();
    }
    {
        unsigned sfx  = cs[t];
        unsigned sfx1 = (t < 255) ? cs[t + 1] : 0u;
        if (sfx >= krem && sfx1 < krem) {
            *out_bin  = chunk * 256 + (unsigned)t;
            *out_rank = krem - sfx1;
        }
    }
    __syncthreads();
}

// =====================================================================================
// k_main: ONE pass, one block per (batch, channel<6, chunk). W = (sig(p6)*m >= 0.5)
// recomputed inline (kills the k_a->k_b dependency and its dispatch). Per iteration,
// 16 dwordx4 (20 for c==0) issued as a cluster and PINNED by sched_barrier(0) so the
// scheduler cannot re-serialize them (rounds 1/4/5/6 all lost this to RP-minimization).
// c==0 blocks additionally produce pos/zero counts and the 3 speculative M=1 L_c sums.
// =====================================================================================
__global__ __launch_bounds__(256) void k_main(
        const float* __restrict__ preds, const int* __restrict__ labels,
        const int* __restrict__ mask,
        float* __restrict__ psumA,           // [BS][3][GXM]  (c==0 blocks)
        unsigned* __restrict__ ppos,         // [BS][GXM]
        unsigned* __restrict__ pzero,        // [BS][GXM]
        float* __restrict__ psumB,           // [BS*6][3][GXM]
        unsigned* __restrict__ done) {
    const int tid = threadIdx.x;
    const int y = blockIdx.y;                // b*6 + c
    const int b = y / 6, c = y % 6;
    const int cb = blockIdx.x;
    const bool c0 = (c == 0);
    if (y == 0 && cb == 0 && tid == 0) *done = 0u;   // re-arm k_sel ticket

    const float* pc = preds + ((size_t)b * NCH + c) * PX;
    const int*   lc = labels + ((size_t)b * NCH + c) * PX;
    const float* p6 = preds + ((size_t)b * NCH + 6) * PX;
    const int*   l6 = labels + ((size_t)b * NCH + 6) * PX;
    const int*   mk = mask + (size_t)b * PX;

    float sn = 0.f, sp = 0.f;
    unsigned slc = 0;
    float a0 = 0.f, a1 = 0.f;
    unsigned a2c = 0, cnt = 0;               // cnt = pos | (zero<<16)

    for (int it = 0; it < ITM; ++it) {
        const int gbase = cb * (NT * UM * ITM) + it * (NT * UM) + tid;
        // ---- load cluster: issue everything, then pin with sched_barrier ----
        float4 P6[UM]; int4 M[UM]; float4 P[UM]; int4 L[UM]; int4 L6[UM];
        #pragma unroll
        for (int q = 0; q < UM; q++) {
            int px = (gbase + q * NT) * 4;
            P6[q] = *(const float4*)(p6 + px);
            M[q]  = *(const int4*)(mk + px);
        }
        #pragma unroll
        for (int q = 0; q < UM; q++) {
            int px = (gbase + q * NT) * 4;
            P[q] = *(const float4*)(pc + px);
            L[q] = *(const int4*)(lc + px);
        }
        if (c0) {
            #pragma unroll
            for (int q = 0; q < UM; q++) {
                int px = (gbase + q * NT) * 4;
                L6[q] = *(const int4*)(l6 + px);
            }
        }
        __builtin_amdgcn_sched_barrier(0);   // loads stay issued ABOVE this line

        #pragma unroll
        for (int q = 0; q < UM; q++) {
            float mm[4]  = {(float)M[q].x, (float)M[q].y, (float)M[q].z, (float)M[q].w};
            float p6a[4] = {P6[q].x, P6[q].y, P6[q].z, P6[q].w};
            float pa[4]  = {P[q].x, P[q].y, P[q].z, P[q].w};
            int   la[4]  = {L[q].x, L[q].y, L[q].z, L[q].w};
            int   l6a[4] = {L6[q].x, L6[q].y, L6[q].z, L6[q].w};
            #pragma unroll
            for (int v = 0; v < 4; v++) {
                float pn = sigf(p6a[v]) * mm[v];
                bool W   = (pn >= 0.5f);
                float s  = sigf(pa[v]);
                bool lw  = W && (la[v] != 0);
                sn += lw ? s : 0.0f;          // sum S*G*W
                sp += W ? s * s : 0.0f;       // sum S*S*W
                slc += lw ? 1u : 0u;          // sum G*G*W (G in {0,1})
                if (c0) {
                    cnt += W ? 1u : (__float_as_uint(pn) == 0u ? 0x10000u : 0u);
                    bool ln = (l6a[v] != 0) && (mm[v] != 0.0f);
                    a0 += ln ? pn : 0.0f;     // spec a0 = sum pn*ln  (M=1)
                    a1 += pn * pn;            // spec a1 = sum pn^2
                    a2c += ln ? 1u : 0u;      // spec a2 = sum ln
                }
            }
        }
    }

    // ---- block reduce ----
    __shared__ float red[4][3];
    __shared__ float redA[4][3];
    __shared__ unsigned redC[4];
    const int lane = tid & 63, wid = tid >> 6;
    float v0 = sn, v1 = sp, v2 = (float)slc;
    wred3_f(v0, v1, v2);
    if (lane == 0) { red[wid][0] = v0; red[wid][1] = v1; red[wid][2] = v2; }
    if (c0) {
        float u0 = a0, u1 = a1, u2 = (float)a2c;
        wred3_f(u0, u1, u2);
        unsigned cr = wred_u(cnt);
        if (lane == 0) { redA[wid][0] = u0; redA[wid][1] = u1; redA[wid][2] = u2; redC[wid] = cr; }
    }
    __syncthreads();
    if (tid < 3) {
        float tot = red[0][tid] + red[1][tid] + red[2][tid] + red[3][tid];
        psumB[((size_t)y * 3 + tid) * GXM + cb] = tot;
    }
    if (c0) {
        if (tid < 3) {
            float tot = redA[0][tid] + redA[1][tid] + redA[2][tid] + redA[3][tid];
            psumA[((size_t)b * 3 + tid) * GXM + cb] = tot;
        }
        if (tid == 3) {
            unsigned ct = redC[0] + redC[1] + redC[2] + redC[3];
            ppos[b * GXM + cb]  = ct & 0xFFFFu;
            pzero[b * GXM + cb] = ct >> 16;
        }
    }
}

// =====================================================================================
// k_sel: 8 blocks, one per batch. Reduce partials; fast path (always hit on bench
// data): thr<=0 or k >= nonzero-negatives -> speculative sums exact. Rare path: solo
// exact selection + rescan. 8-block ticket emits final losses.
// =====================================================================================
__global__ __launch_bounds__(256) void k_sel(
        const float* __restrict__ preds, const int* __restrict__ labels,
        const int* __restrict__ mask,
        const float* __restrict__ psumA, const float* __restrict__ psumB,
        const unsigned* __restrict__ ppos, const unsigned* __restrict__ pzero,
        unsigned* __restrict__ histws, unsigned* __restrict__ chunkws,
        float* __restrict__ lcls, unsigned* __restrict__ done,
        float* __restrict__ out) {
    const int tid = threadIdx.x;
    const int b = blockIdx.x;
    const int lane = tid & 63, wid = tid >> 6;

    // ---- reduce counts + 21 sums into LDS ----
    __shared__ float S[21];
    __shared__ unsigned C[2];
    if (tid < 21) S[tid] = 0.f;
    if (tid < 2) C[tid] = 0u;
    __syncthreads();
    {
        unsigned pc = 0, zc = 0;
        for (int i = tid; i < GXM; i += NT) {
            pc += ppos[b * GXM + i];
            zc += pzero[b * GXM + i];
        }
        pc = wred_u(pc); zc = wred_u(zc);
        if (lane == 0) { atomicAdd(&C[0], pc); atomicAdd(&C[1], zc); }
    }
    for (int i = tid; i < 3 * GXM; i += NT)
        atomicAdd(&S[18 + i / GXM], psumA[(size_t)b * 3 * GXM + i]);
    for (int i = tid; i < 6 * 3 * GXM; i += NT) {
        int cch = i / (3 * GXM);
        int j   = (i / GXM) % 3;
        atomicAdd(&S[j * 6 + cch], psumB[(size_t)b * 6 * 3 * GXM + i]);
    }
    __syncthreads();
    const unsigned np = C[0], zc = C[1];

    const unsigned k = np * 3u;
    const bool active = ((unsigned)PX - np > k) && (k > 0u);
    const unsigned nzneg = (unsigned)PX - np - zc;   // negatives with pn > 0

    float Lc_b;
    if (!active || k >= nzneg) {
        // thr <= 0: excluded pixels all have pn==0 => mask==0 => zero contribution.
        Lc_b = 1.0f - 2.0f * S[18] / (S[19] + S[20] + EPSF);
    } else {
        // -------- RARE exact path (not hit by bench data; correctness only) --------
        unsigned* h1 = histws + (size_t)b * NBIN;
        unsigned* c1 = chunkws + (size_t)b * NCHK;
        const float* pr6 = preds + ((size_t)b * NCH + 6) * PX;
        const int*   lb6 = labels + ((size_t)b * NCH + 6) * PX;
        const int*   mk  = mask + (size_t)b * PX;

        for (int j = tid; j < NBIN; j += NT) h1[j] = 0u;
        for (int j = tid; j < NCHK; j += NT) c1[j] = 0u;
        __syncthreads();
        for (int gg = tid; gg < PX; gg += NT) {
            float pnx = sigf(pr6[gg]) * (float)mk[gg];
            if (pnx < 0.5f) {
                unsigned bits = __float_as_uint(pnx);
                if (bits) {
                    atomicAdd(&h1[bits >> 16], 1u);
                    atomicAdd(&c1[bits >> 24], 1u);
                }
            }
        }
        __syncthreads();
        if (tid == 0) { atomicAdd(&h1[0], zc); atomicAdd(&c1[0], zc); }
        __syncthreads();

        __shared__ unsigned rb, rr, rb2, rr2;
        select2(c1, h1, k, &rb, &rr);
        float thrv;
        if (rb == 0u) {
            thrv = 0.0f;
        } else {
            unsigned hi = rb;
            for (int j = tid; j < NBIN; j += NT) h1[j] = 0u;
            for (int j = tid; j < NCHK; j += NT) c1[j] = 0u;
            __syncthreads();
            for (int gg = tid; gg < PX; gg += NT) {
                float pnx = sigf(pr6[gg]) * (float)mk[gg];
                if (pnx < 0.5f) {
                    unsigned bits = __float_as_uint(pnx);
                    if (bits && (bits >> 16) == hi) {
                        unsigned lo = bits & 0xFFFFu;
                        atomicAdd(&h1[lo], 1u);
                        atomicAdd(&c1[lo >> 8], 1u);
                    }
                }
            }
            __syncthreads();
            select2(c1, h1, rr, &rb2, &rr2);
            thrv = __uint_as_float((hi << 16) | rb2);
        }
        float a0 = 0.f, a1 = 0.f, a2 = 0.f;
        for (int gg = tid; gg < PX; gg += NT) {
            float m   = (float)mk[gg];
            float pnx = sigf(pr6[gg]) * m;
            if (pnx >= thrv) {
                float ln = (float)lb6[gg] * m;
                a0 += pnx * ln;
                a1 += pnx * pnx;
                a2 += ln;
            }
        }
        __shared__ float aR[4][3];
        wred3_f(a0, a1, a2);
        if (lane == 0) { aR[wid][0] = a0; aR[wid][1] = a1; aR[wid][2] = a2; }
        __syncthreads();
        float A0 = aR[0][0] + aR[1][0] + aR[2][0] + aR[3][0];
        float A1 = aR[0][1] + aR[1][1] + aR[2][1] + aR[3][1];
        float A2 = aR[0][2] + aR[1][2] + aR[2][2] + aR[3][2];
        Lc_b = 1.0f - 2.0f * A0 / (A1 + A2 + EPSF);
    }

    float ls_acc = 0.f;
    #pragma unroll
    for (int c = 0; c < 6; c++)
        ls_acc += (2.0f * S[c]) / (S[6 + c] + S[12 + c] + EPSF);
    float Ls_b = 1.0f - ls_acc * (1.0f / 6.0f);

    if (tid == 0) {
        lcls[b * 2]     = Lc_b;
        lcls[b * 2 + 1] = Ls_b;
    }

    // ---- 8-block ticket -> last block emits final losses ----
    __shared__ unsigned tick;
    if (tid == 0) {
        __threadfence();
        tick = atomicAdd(done, 1u);
    }
    __syncthreads();
    if (tick != (unsigned)(BS - 1)) return;
    __threadfence();

    float Lc = 0.f, Ls = 0.f;
    if (tid < BS) { Lc = lcls[tid * 2]; Ls = lcls[tid * 2 + 1]; }
    #pragma unroll
    for (int o = 4; o; o >>= 1) { Lc += __shfl_down(Lc, o); Ls += __shfl_down(Ls, o); }
    if (tid == 0) {
        float lc_m = Lc * (1.0f / (float)BS);
        float ls_m = Ls * (1.0f / (float)BS);
        out[0] = lc_m;
        out[1] = ls_m;
        out[2] = 0.7f * lc_m + 0.3f * ls_m;
    }
}

extern "C" void kernel_launch(void* const* d_in, const int* in_sizes, int n_in,
                              void* d_out, int out_size, void* d_ws, size_t ws_size,
                              hipStream_t stream) {
    const float* preds = (const float*)d_in[0];
    const int* labels  = (const int*)d_in[1];
    const int* mask    = (const int*)d_in[2];
    float* out = (float*)d_out;

    // workspace (nothing needs pre-zeroing)
    float*    psumA   = (float*)d_ws;                            // BS*3*GXM
    unsigned* ppos    = (unsigned*)(psumA + (size_t)BS * 3 * GXM);   // BS*GXM
    unsigned* pzero   = ppos + BS * GXM;                         // BS*GXM
    float*    psumB   = (float*)(pzero + BS * GXM);              // BS*6*3*GXM
    unsigned* done    = (unsigned*)(psumB + (size_t)BS * 18 * GXM);  // 1 (pad 8)
    float*    lcls    = (float*)(done + 8);                      // BS*2
    unsigned* histws  = (unsigned*)(lcls + BS * 2);              // BS*NBIN (rare)
    unsigned* chunkws = histws + (size_t)BS * NBIN;              // BS*NCHK (rare)

    hipLaunchKernelGGL(k_main, dim3(GXM, BS * 6), dim3(NT), 0, stream,
                       preds, labels, mask, psumA, ppos, pzero, psumB, done);

    hipLaunchKernelGGL(k_sel, dim3(BS), dim3(NT), 0, stream,
                       preds, labels, mask, psumA, psumB, ppos, pzero,
                       histws, chunkws, lcls, done, out);
}